// Round 7
// baseline (3839.851 us; speedup 1.0000x reference)
//
#include <hip/hip_runtime.h>
#include <hip/hip_fp16.h>

#define NEG_SLOPE 0.2f
#define EPSV 1e-16f
#define BCAP 3072   // bucket capacity: mean 2046 edges/bucket, 22 sigma margin

__device__ __forceinline__ float leaky_relu(float v) {
    return v > 0.f ? v : NEG_SLOPE * v;
}

// ===================== GEMM =====================
// h = X @ W  (X: [nrows,128] XT (fp32 or fp16), W: [128,HC] fp32) -> Hout fp16.
template<int HC, typename XT>
__global__ __launch_bounds__(256)
void gemm_kernel(const XT* __restrict__ X, const float* __restrict__ W,
                 __half* __restrict__ Hout, int nrows)
{
    constexpr int CG = HC / 8;       // col groups (8 cols per thread)
    constexpr int ROWS = 512 / CG;   // rows per block
    __shared__ float Xs[ROWS][132];
    __shared__ float Ws[64 * HC];

    const int t = threadIdx.x;
    const int rowbase = blockIdx.x * ROWS;

    if constexpr (sizeof(XT) == 4) {
        for (int i = t * 4; i < ROWS * 128; i += 256 * 4) {
            const int r = i >> 7;
            const int c = i & 127;
            const int n = rowbase + r;
            float4 v = make_float4(0.f, 0.f, 0.f, 0.f);
            if (n < nrows) v = *(const float4*)&X[(size_t)n * 128 + c];
            *(float4*)&Xs[r][c] = v;
        }
    } else {
        for (int i = t * 8; i < ROWS * 128; i += 256 * 8) {
            const int r = i >> 7;
            const int c = i & 127;
            const int n = rowbase + r;
            union { float4 f4; __half2 h2[4]; } u;
            u.f4 = make_float4(0.f, 0.f, 0.f, 0.f);
            if (n < nrows) u.f4 = *(const float4*)&X[(size_t)n * 128 + c];
            const float2 f0 = __half22float2(u.h2[0]);
            const float2 f1 = __half22float2(u.h2[1]);
            const float2 f2 = __half22float2(u.h2[2]);
            const float2 f3 = __half22float2(u.h2[3]);
            *(float4*)&Xs[r][c]     = make_float4(f0.x, f0.y, f1.x, f1.y);
            *(float4*)&Xs[r][c + 4] = make_float4(f2.x, f2.y, f3.x, f3.y);
        }
    }

    const int cg = t % CG;
    const int rg = t / CG;
    const int r0 = rg * 2;
    const int c0 = cg * 8;

    float acc[2][8];
    #pragma unroll
    for (int i = 0; i < 2; ++i)
        #pragma unroll
        for (int j = 0; j < 8; ++j) acc[i][j] = 0.f;

    for (int kc = 0; kc < 2; ++kc) {
        __syncthreads();
        for (int i = t * 4; i < 64 * HC; i += 256 * 4)
            *(float4*)&Ws[i] = *(const float4*)&W[kc * 64 * HC + i];
        __syncthreads();
        #pragma unroll 8
        for (int kk = 0; kk < 64; ++kk) {
            const float x0 = Xs[r0][kc * 64 + kk];
            const float x1 = Xs[r0 + 1][kc * 64 + kk];
            const float4 w0 = *(const float4*)&Ws[kk * HC + c0];
            const float4 w1 = *(const float4*)&Ws[kk * HC + c0 + 4];
            acc[0][0] = fmaf(x0, w0.x, acc[0][0]);
            acc[0][1] = fmaf(x0, w0.y, acc[0][1]);
            acc[0][2] = fmaf(x0, w0.z, acc[0][2]);
            acc[0][3] = fmaf(x0, w0.w, acc[0][3]);
            acc[0][4] = fmaf(x0, w1.x, acc[0][4]);
            acc[0][5] = fmaf(x0, w1.y, acc[0][5]);
            acc[0][6] = fmaf(x0, w1.z, acc[0][6]);
            acc[0][7] = fmaf(x0, w1.w, acc[0][7]);
            acc[1][0] = fmaf(x1, w0.x, acc[1][0]);
            acc[1][1] = fmaf(x1, w0.y, acc[1][1]);
            acc[1][2] = fmaf(x1, w0.z, acc[1][2]);
            acc[1][3] = fmaf(x1, w0.w, acc[1][3]);
            acc[1][4] = fmaf(x1, w1.x, acc[1][4]);
            acc[1][5] = fmaf(x1, w1.y, acc[1][5]);
            acc[1][6] = fmaf(x1, w1.z, acc[1][6]);
            acc[1][7] = fmaf(x1, w1.w, acc[1][7]);
        }
    }

    #pragma unroll
    for (int i = 0; i < 2; ++i) {
        const int n = rowbase + r0 + i;
        if (n < nrows) {
            union { __half2 h2[4]; float4 f4; } u;
            u.h2[0] = __floats2half2_rn(acc[i][0], acc[i][1]);
            u.h2[1] = __floats2half2_rn(acc[i][2], acc[i][3]);
            u.h2[2] = __floats2half2_rn(acc[i][4], acc[i][5]);
            u.h2[3] = __floats2half2_rn(acc[i][6], acc[i][7]);
            *(float4*)&Hout[(size_t)n * HC + c0] = u.f4;
        }
    }
}

// ===================== per-node attention coefficients (fp16 h) =====================
template<int H>
__global__ __launch_bounds__(256)
void alpha_kernel(const __half* __restrict__ hbuf, const float* __restrict__ a_src,
                  const float* __restrict__ a_dst, float* __restrict__ as_,
                  float* __restrict__ ad_, int n)
{
    const int tid = blockIdx.x * 256 + threadIdx.x;
    if (tid >= n * H) return;
    const int node = tid / H;
    const int h = tid % H;
    const __half2* hp = (const __half2*)(hbuf + (size_t)node * (H * 32) + h * 32);
    const float2* sp = (const float2*)(a_src + h * 32);
    const float2* dp = (const float2*)(a_dst + h * 32);
    float accs = 0.f, accd = 0.f;
    #pragma unroll
    for (int j = 0; j < 16; ++j) {
        const float2 v = __half22float2(hp[j]);
        const float2 sa = sp[j];
        const float2 da = dp[j];
        accs += v.x * sa.x + v.y * sa.y;
        accd += v.x * da.x + v.y * da.y;
    }
    as_[tid] = accs;
    ad_[tid] = accd;
}

// ===================== bucket build (once per launch) =====================
// bucket b = dst>>7 (128 nodes each). Appends (src | dlocal<<20); sequential
// writes per bucket -> full-line writebacks (kills the 16x write amplification
// of the old per-node scatter). Self-loops are NOT appended (epilogue handles).
__global__ __launch_bounds__(256)
void bucket_append_kernel(const int* __restrict__ srcs, const int* __restrict__ dsts,
                          int E, int* __restrict__ bcur, unsigned* __restrict__ packed)
{
    const int base = blockIdx.x * 2048 + threadIdx.x;
    #pragma unroll
    for (int k = 0; k < 8; ++k) {
        const int e = base + k * 256;
        if (e < E) {
            const int s = srcs[e];
            const int d = dsts[e];
            const int b = d >> 7;
            const unsigned entry = (unsigned)s | ((unsigned)(d & 127) << 20);
            const int p = atomicAdd(&bcur[b], 1);
            if (p < BCAP) packed[(size_t)b * BCAP + p] = entry;
        }
    }
}

// ===================== fused edge softmax + aggregation per bucket =====================
// one block per bucket (128 dst nodes). Per-node accumulators + denominators in LDS
// (cross-wave LDS atomics). alpha = exp(e)/sum(exp(e)) (shift-free; |e|<~5 bounded by
// data). Epilogue fuses: self-loop contribution + normalize + bias + (ReLU+fp16 | fp32 out).
template<int H>
__global__ __launch_bounds__(256)
void bucket_gather_kernel(const unsigned* __restrict__ packed, const int* __restrict__ bcnt,
                          const float* __restrict__ as_, const float* __restrict__ ad_,
                          const __half* __restrict__ hbuf, const float* __restrict__ bias,
                          __half* __restrict__ hin, float* __restrict__ outf, int N)
{
    constexpr int HC = H * 32;
    __shared__ float acc[128 * HC];     // [dlocal][ch]
    __shared__ float sden[128 * H];     // [dlocal][h]
    __shared__ float ads[128 * H];      // ad_ cache
    __shared__ float pS[4][64 * H];
    __shared__ unsigned sS[4][64];

    const int t = threadIdx.x;
    const int w = t >> 6;
    const int lane = t & 63;
    const int b = blockIdx.x;
    const int nbase = b * 128;

    for (int i = t; i < 128 * HC; i += 256) acc[i] = 0.f;
    for (int i = t; i < 128 * H; i += 256) {
        sden[i] = 0.f;
        const int node = nbase + i / H;
        ads[i] = (node < N) ? ad_[node * H + (i % H)] : 0.f;
    }
    __syncthreads();

    const int cnt = min(bcnt[b], BCAP);
    const unsigned* bp = packed + (size_t)b * BCAP;
    const int h4 = lane >> 4;      // head for H=4 aggregation (ch pair = lane*2)
    const int c1 = lane & 31;      // channel for H=1
    const int half_ = lane >> 5;   // edge parity for H=1

    for (int cb = w * 64; cb < cnt; cb += 256) {
        const int cntc = min(64, cnt - cb);
        unsigned entry = 0;
        float p0 = 0.f, p1 = 0.f, p2 = 0.f, p3 = 0.f;
        if (lane < cntc) {
            entry = bp[cb + lane];
            const int src = entry & 0xFFFFF;
            const int dl = entry >> 20;
            if (H == 4) {
                const float4 a = *(const float4*)&as_[src * 4];
                p0 = __expf(leaky_relu(a.x + ads[dl * 4 + 0]));
                p1 = __expf(leaky_relu(a.y + ads[dl * 4 + 1]));
                p2 = __expf(leaky_relu(a.z + ads[dl * 4 + 2]));
                p3 = __expf(leaky_relu(a.w + ads[dl * 4 + 3]));
                atomicAdd(&sden[dl * 4 + 0], p0);
                atomicAdd(&sden[dl * 4 + 1], p1);
                atomicAdd(&sden[dl * 4 + 2], p2);
                atomicAdd(&sden[dl * 4 + 3], p3);
            } else {
                p0 = __expf(leaky_relu(as_[src] + ads[dl]));
                atomicAdd(&sden[dl], p0);
            }
        }
        __builtin_amdgcn_wave_barrier();
        sS[w][lane] = entry;
        if (H == 4) {
            *(float4*)&pS[w][lane * 4] = make_float4(p0, p1, p2, p3);
        } else {
            pS[w][lane] = p0;
        }
        __builtin_amdgcn_wave_barrier();
        if (H == 4) {
            // e2 wave-uniform -> readfirstlane legal (scalar-base h loads)
            #pragma unroll 8
            for (int e2 = 0; e2 < cntc; ++e2) {
                const unsigned en = __builtin_amdgcn_readfirstlane(sS[w][e2]);
                const int src = en & 0xFFFFF;
                const int dl = en >> 20;
                const float pp = pS[w][e2 * 4 + h4];
                const float2 v = __half22float2(
                    *(const __half2*)&hbuf[(size_t)src * 128 + lane * 2]);
                atomicAdd(&acc[dl * 128 + lane * 2],     pp * v.x);
                atomicAdd(&acc[dl * 128 + lane * 2 + 1], pp * v.y);
            }
        } else {
            // e2 diverges across half-waves -> per-lane LDS read (NOT readfirstlane)
            #pragma unroll 8
            for (int e2 = half_; e2 < cntc; e2 += 2) {
                const unsigned en = sS[w][e2];
                const int src = en & 0xFFFFF;
                const int dl = en >> 20;
                const float pp = pS[w][e2];
                atomicAdd(&acc[dl * 32 + c1],
                          pp * __half2float(hbuf[(size_t)src * 32 + c1]));
            }
        }
        __builtin_amdgcn_wave_barrier();   // pS/sS reused next chunk
    }
    __syncthreads();

    // ---- epilogue: self-loop + normalize + bias (+ReLU/fp16 for H=4) ----
    if (H == 4) {
        for (int g = 0; g < 128; g += 4) {
            const int dl = g + w;
            const int node = nbase + dl;
            if (node < N) {
                const float4 a = *(const float4*)&as_[node * 4];
                float ps[4];
                ps[0] = __expf(leaky_relu(a.x + ads[dl * 4 + 0]));
                ps[1] = __expf(leaky_relu(a.y + ads[dl * 4 + 1]));
                ps[2] = __expf(leaky_relu(a.z + ads[dl * 4 + 2]));
                ps[3] = __expf(leaky_relu(a.w + ads[dl * 4 + 3]));
                const float ph = ps[h4];
                const float den = sden[dl * 4 + h4] + ph;
                const float inv = 1.f / (den + EPSV);
                const float2 hs = __half22float2(
                    *(const __half2*)&hbuf[(size_t)node * 128 + lane * 2]);
                const float2 bb = *(const float2*)&bias[lane * 2];
                const float a0 = acc[dl * 128 + lane * 2]     + ph * hs.x;
                const float a1 = acc[dl * 128 + lane * 2 + 1] + ph * hs.y;
                const float o0 = fmaxf(fmaf(a0, inv, bb.x), 0.f);
                const float o1 = fmaxf(fmaf(a1, inv, bb.y), 0.f);
                *(__half2*)&hin[(size_t)node * 128 + lane * 2] = __floats2half2_rn(o0, o1);
            }
        }
    } else {
        for (int g = 0; g < 128; g += 8) {
            const int dl = g + (t >> 5);
            const int node = nbase + dl;
            if (node < N) {
                const float ps = __expf(leaky_relu(as_[node] + ads[dl]));
                const float den = sden[dl] + ps;
                const float hv = __half2float(hbuf[(size_t)node * 32 + c1]);
                outf[(size_t)node * 32 + c1] =
                    (acc[dl * 32 + c1] + ps * hv) / (den + EPSV) + bias[c1];
            }
        }
    }
}

extern "C" void kernel_launch(void* const* d_in, const int* in_sizes, int n_in,
                              void* d_out, int out_size, void* d_ws, size_t ws_size,
                              hipStream_t stream)
{
    const float* x     = (const float*)d_in[0];
    const int*   ei    = (const int*)d_in[1];
    const float* W0    = (const float*)d_in[2];
    const float* asrc0 = (const float*)d_in[3];
    const float* adst0 = (const float*)d_in[4];
    const float* b0    = (const float*)d_in[5];
    const float* W1    = (const float*)d_in[6];
    const float* asrc1 = (const float*)d_in[7];
    const float* adst1 = (const float*)d_in[8];
    const float* b1    = (const float*)d_in[9];
    const float* W2    = (const float*)d_in[10];
    const float* asrc2 = (const float*)d_in[11];
    const float* adst2 = (const float*)d_in[12];
    const float* b2    = (const float*)d_in[13];

    const int N = in_sizes[0] / 128;     // 100000
    const int E = in_sizes[1] / 2;       // 1600000
    const int NB = (N + 127) / 128;      // buckets of 128 dst nodes
    const int* srcs = ei;
    const int* dsts = ei + E;

    __half* hbuf    = (__half*)d_ws;                      // N*128 fp16 (GEMM out)
    __half* hin     = hbuf + (size_t)N * 128;             // N*128 fp16 (gather out)
    float* as_      = (float*)(hin + (size_t)N * 128);    // N*4
    float* ad_      = as_ + (size_t)N * 4;                // N*4
    int* bcur       = (int*)(ad_ + (size_t)N * 4);        // NB
    unsigned* packed = (unsigned*)(bcur + NB);            // NB*BCAP

    const dim3 blk(256);
    const int gemm128_grid = (N + 31) / 32;
    const int gemm32_grid  = (N + 127) / 128;
    const int nodeH_grid   = (N * 4 + 255) / 256;
    const int node1_grid   = (N + 255) / 256;
    const int edgeE8_grid  = (E + 2047) / 2048;

    // ---------------- bucket build (dst-bucketed edge lists), once ----------------
    hipMemsetAsync(bcur, 0, (size_t)NB * 4, stream);
    bucket_append_kernel<<<edgeE8_grid, blk, 0, stream>>>(srcs, dsts, E, bcur, packed);

    // ---------------- layer 0 (H=4, C=32) ----------------
    gemm_kernel<128, float><<<gemm128_grid, blk, 0, stream>>>(x, W0, hbuf, N);
    alpha_kernel<4><<<nodeH_grid, blk, 0, stream>>>(hbuf, asrc0, adst0, as_, ad_, N);
    bucket_gather_kernel<4><<<NB, blk, 0, stream>>>(packed, bcur, as_, ad_, hbuf, b0, hin, nullptr, N);

    // ---------------- layer 1 (H=4, C=32) ----------------
    gemm_kernel<128, __half><<<gemm128_grid, blk, 0, stream>>>(hin, W1, hbuf, N);
    alpha_kernel<4><<<nodeH_grid, blk, 0, stream>>>(hbuf, asrc1, adst1, as_, ad_, N);
    bucket_gather_kernel<4><<<NB, blk, 0, stream>>>(packed, bcur, as_, ad_, hbuf, b1, hin, nullptr, N);

    // ---------------- layer 2 (H=1, C=32) ----------------
    gemm_kernel<32, __half><<<gemm32_grid, blk, 0, stream>>>(hin, W2, hbuf, N);
    alpha_kernel<1><<<node1_grid, blk, 0, stream>>>(hbuf, asrc2, adst2, as_, ad_, N);
    bucket_gather_kernel<1><<<NB, blk, 0, stream>>>(packed, bcur, as_, ad_, hbuf, b2, nullptr, (float*)d_out, N);
}

// Round 8
// 900.850 us; speedup vs baseline: 4.2625x; 4.2625x over previous
//
#include <hip/hip_runtime.h>
#include <hip/hip_fp16.h>

#define NEG_SLOPE 0.2f
#define EPSV 1e-16f
#define BCAP 3072   // bucket capacity: mean 2046 edges/bucket, ~22 sigma margin

__device__ __forceinline__ float leaky_relu(float v) {
    return v > 0.f ? v : NEG_SLOPE * v;
}

// ===================== GEMM =====================
// h = X @ W  (X: [nrows,128] XT (fp32 or fp16), W: [128,HC] fp32) -> Hout fp16.
template<int HC, typename XT>
__global__ __launch_bounds__(256)
void gemm_kernel(const XT* __restrict__ X, const float* __restrict__ W,
                 __half* __restrict__ Hout, int nrows)
{
    constexpr int CG = HC / 8;       // col groups (8 cols per thread)
    constexpr int ROWS = 512 / CG;   // rows per block
    __shared__ float Xs[ROWS][132];
    __shared__ float Ws[64 * HC];

    const int t = threadIdx.x;
    const int rowbase = blockIdx.x * ROWS;

    if constexpr (sizeof(XT) == 4) {
        for (int i = t * 4; i < ROWS * 128; i += 256 * 4) {
            const int r = i >> 7;
            const int c = i & 127;
            const int n = rowbase + r;
            float4 v = make_float4(0.f, 0.f, 0.f, 0.f);
            if (n < nrows) v = *(const float4*)&X[(size_t)n * 128 + c];
            *(float4*)&Xs[r][c] = v;
        }
    } else {
        for (int i = t * 8; i < ROWS * 128; i += 256 * 8) {
            const int r = i >> 7;
            const int c = i & 127;
            const int n = rowbase + r;
            union { float4 f4; __half2 h2[4]; } u;
            u.f4 = make_float4(0.f, 0.f, 0.f, 0.f);
            if (n < nrows) u.f4 = *(const float4*)&X[(size_t)n * 128 + c];
            const float2 f0 = __half22float2(u.h2[0]);
            const float2 f1 = __half22float2(u.h2[1]);
            const float2 f2 = __half22float2(u.h2[2]);
            const float2 f3 = __half22float2(u.h2[3]);
            *(float4*)&Xs[r][c]     = make_float4(f0.x, f0.y, f1.x, f1.y);
            *(float4*)&Xs[r][c + 4] = make_float4(f2.x, f2.y, f3.x, f3.y);
        }
    }

    const int cg = t % CG;
    const int rg = t / CG;
    const int r0 = rg * 2;
    const int c0 = cg * 8;

    float acc[2][8];
    #pragma unroll
    for (int i = 0; i < 2; ++i)
        #pragma unroll
        for (int j = 0; j < 8; ++j) acc[i][j] = 0.f;

    for (int kc = 0; kc < 2; ++kc) {
        __syncthreads();
        for (int i = t * 4; i < 64 * HC; i += 256 * 4)
            *(float4*)&Ws[i] = *(const float4*)&W[kc * 64 * HC + i];
        __syncthreads();
        #pragma unroll 8
        for (int kk = 0; kk < 64; ++kk) {
            const float x0 = Xs[r0][kc * 64 + kk];
            const float x1 = Xs[r0 + 1][kc * 64 + kk];
            const float4 w0 = *(const float4*)&Ws[kk * HC + c0];
            const float4 w1 = *(const float4*)&Ws[kk * HC + c0 + 4];
            acc[0][0] = fmaf(x0, w0.x, acc[0][0]);
            acc[0][1] = fmaf(x0, w0.y, acc[0][1]);
            acc[0][2] = fmaf(x0, w0.z, acc[0][2]);
            acc[0][3] = fmaf(x0, w0.w, acc[0][3]);
            acc[0][4] = fmaf(x0, w1.x, acc[0][4]);
            acc[0][5] = fmaf(x0, w1.y, acc[0][5]);
            acc[0][6] = fmaf(x0, w1.z, acc[0][6]);
            acc[0][7] = fmaf(x0, w1.w, acc[0][7]);
            acc[1][0] = fmaf(x1, w0.x, acc[1][0]);
            acc[1][1] = fmaf(x1, w0.y, acc[1][1]);
            acc[1][2] = fmaf(x1, w0.z, acc[1][2]);
            acc[1][3] = fmaf(x1, w0.w, acc[1][3]);
            acc[1][4] = fmaf(x1, w1.x, acc[1][4]);
            acc[1][5] = fmaf(x1, w1.y, acc[1][5]);
            acc[1][6] = fmaf(x1, w1.z, acc[1][6]);
            acc[1][7] = fmaf(x1, w1.w, acc[1][7]);
        }
    }

    #pragma unroll
    for (int i = 0; i < 2; ++i) {
        const int n = rowbase + r0 + i;
        if (n < nrows) {
            union { __half2 h2[4]; float4 f4; } u;
            u.h2[0] = __floats2half2_rn(acc[i][0], acc[i][1]);
            u.h2[1] = __floats2half2_rn(acc[i][2], acc[i][3]);
            u.h2[2] = __floats2half2_rn(acc[i][4], acc[i][5]);
            u.h2[3] = __floats2half2_rn(acc[i][6], acc[i][7]);
            *(float4*)&Hout[(size_t)n * HC + c0] = u.f4;
        }
    }
}

// ===================== per-node attention coefficients (fp16 h) =====================
template<int H>
__global__ __launch_bounds__(256)
void alpha_kernel(const __half* __restrict__ hbuf, const float* __restrict__ a_src,
                  const float* __restrict__ a_dst, float* __restrict__ as_,
                  float* __restrict__ ad_, int n)
{
    const int tid = blockIdx.x * 256 + threadIdx.x;
    if (tid >= n * H) return;
    const int node = tid / H;
    const int h = tid % H;
    const __half2* hp = (const __half2*)(hbuf + (size_t)node * (H * 32) + h * 32);
    const float2* sp = (const float2*)(a_src + h * 32);
    const float2* dp = (const float2*)(a_dst + h * 32);
    float accs = 0.f, accd = 0.f;
    #pragma unroll
    for (int j = 0; j < 16; ++j) {
        const float2 v = __half22float2(hp[j]);
        const float2 sa = sp[j];
        const float2 da = dp[j];
        accs += v.x * sa.x + v.y * sa.y;
        accd += v.x * da.x + v.y * da.y;
    }
    as_[tid] = accs;
    ad_[tid] = accd;
}

// ===================== CSR build via 128-node buckets (once per launch) ==========
// Phase 1: append (src | dlocal<<20) to dst-bucket -- sequential writes per bucket
// (full-line writebacks; kills the 16x line amplification of direct scatter).
__global__ __launch_bounds__(256)
void bucket_append_kernel(const int* __restrict__ srcs, const int* __restrict__ dsts,
                          int E, int* __restrict__ bcur, unsigned* __restrict__ packed)
{
    const int base = blockIdx.x * 2048 + threadIdx.x;
    #pragma unroll
    for (int k = 0; k < 8; ++k) {
        const int e = base + k * 256;
        if (e < E) {
            const int s = srcs[e];
            const int d = dsts[e];
            const int b = d >> 7;
            const unsigned entry = (unsigned)s | ((unsigned)(d & 127) << 20);
            const int p = atomicAdd(&bcur[b], 1);
            if (p < BCAP) packed[(size_t)b * BCAP + p] = entry;
        }
    }
}

// Phase 2: per-bucket LDS histogram (init 1 = self-loop) -> counts, sequential writes.
__global__ __launch_bounds__(256)
void bucket_count_kernel(const unsigned* __restrict__ packed, const int* __restrict__ bcur,
                         int* __restrict__ counts, int N)
{
    __shared__ int cnt[128];
    const int t = threadIdx.x;
    const int b = blockIdx.x;
    const int nbase = b * 128;
    if (t < 128) cnt[t] = 1;   // self-loop
    __syncthreads();
    const int n = min(bcur[b], BCAP);
    const unsigned* bp = packed + (size_t)b * BCAP;
    for (int i = t; i < n; i += 256)
        atomicAdd(&cnt[bp[i] >> 20], 1);
    __syncthreads();
    if (t < 128 && nbase + t < N) counts[nbase + t] = cnt[t];
}

__global__ __launch_bounds__(256)
void scan1_kernel(const int* __restrict__ in, int* __restrict__ out,
                  int* __restrict__ bsums, int n)
{
    __shared__ int lds[256];
    const int t = threadIdx.x;
    const int base = blockIdx.x * 1024 + t * 4;
    int v0 = 0, v1 = 0, v2 = 0, v3 = 0;
    if (base + 0 < n) v0 = in[base + 0];
    if (base + 1 < n) v1 = in[base + 1];
    if (base + 2 < n) v2 = in[base + 2];
    if (base + 3 < n) v3 = in[base + 3];
    const int tsum = v0 + v1 + v2 + v3;
    lds[t] = tsum;
    __syncthreads();
    for (int off = 1; off < 256; off <<= 1) {
        const int y = (t >= off) ? lds[t - off] : 0;
        __syncthreads();
        lds[t] += y;
        __syncthreads();
    }
    int excl = lds[t] - tsum;
    if (t == 255) bsums[blockIdx.x] = lds[255];
    if (base + 0 < n) out[base + 0] = excl; excl += v0;
    if (base + 1 < n) out[base + 1] = excl; excl += v1;
    if (base + 2 < n) out[base + 2] = excl; excl += v2;
    if (base + 3 < n) out[base + 3] = excl;
}

__global__ __launch_bounds__(256)
void scan2_kernel(int* __restrict__ bsums, int nb)
{
    __shared__ int lds[256];
    const int t = threadIdx.x;
    const int v = (t < nb) ? bsums[t] : 0;
    lds[t] = v;
    __syncthreads();
    for (int off = 1; off < 256; off <<= 1) {
        const int y = (t >= off) ? lds[t - off] : 0;
        __syncthreads();
        lds[t] += y;
        __syncthreads();
    }
    if (t < nb) bsums[t] = lds[t] - v;   // exclusive
}

__global__ __launch_bounds__(256)
void scan3_kernel(int* __restrict__ row_ptr, const int* __restrict__ bsums,
                  int n, int etot)
{
    const int idx = blockIdx.x * 256 + threadIdx.x;
    if (idx < n) row_ptr[idx] += bsums[idx >> 10];
    if (idx == n) row_ptr[n] = etot;
}

// Phase 3: per-bucket scatter into exact CSR. LDS cursors seeded from row_ptr;
// col writes land in the bucket's CONTIGUOUS ~8KB CSR span -> no line amplification.
// Self-loops inserted here too.
__global__ __launch_bounds__(256)
void bucket_scatter_kernel(const unsigned* __restrict__ packed, const int* __restrict__ bcur,
                           const int* __restrict__ row_ptr, int* __restrict__ col, int N)
{
    __shared__ int cur[128];
    const int t = threadIdx.x;
    const int b = blockIdx.x;
    const int nbase = b * 128;
    if (t < 128 && nbase + t < N) cur[t] = row_ptr[nbase + t];
    __syncthreads();
    if (t < 128 && nbase + t < N) {            // self-loop
        const int p = atomicAdd(&cur[t], 1);
        col[p] = nbase + t;
    }
    const int n = min(bcur[b], BCAP);
    const unsigned* bp = packed + (size_t)b * BCAP;
    for (int i = t; i < n; i += 256) {
        const unsigned en = bp[i];
        const int p = atomicAdd(&cur[en >> 20], 1);
        col[p] = en & 0xFFFFF;
    }
}

// ===================== fused edge softmax + aggregation + next-layer input prep =====
// one wave per destination node; alpha = exp(e)/sum(exp(e)) (shift-free; data bounds
// |e|<~5 so no overflow). Epilogue fuses normalize + bias + (ReLU+fp16 for H=4 |
// final fp32 out for H=1).
// NOTE: readfirstlane on sS[...] legal ONLY for wave-uniform index (H==4 path).
template<int H>
__global__ __launch_bounds__(256)
void gather_kernel(const int* __restrict__ row_ptr, const int* __restrict__ col,
                   const float* __restrict__ as_, const float* __restrict__ ad_,
                   const __half* __restrict__ hbuf, const float* __restrict__ bias,
                   __half* __restrict__ hin, float* __restrict__ outf, int N)
{
    __shared__ float pS[4][64 * H];
    __shared__ int   sS[4][64];
    const int w = threadIdx.x >> 6;
    const int lane = threadIdx.x & 63;
    const int d = blockIdx.x * 4 + w;
    if (d >= N) return;
    const int jb = __builtin_amdgcn_readfirstlane(row_ptr[d]);
    const int je = __builtin_amdgcn_readfirstlane(row_ptr[d + 1]);

    float ad0 = 0.f, ad1 = 0.f, ad2 = 0.f, ad3 = 0.f;
    if (H == 4) {
        const float4 adv = *(const float4*)&ad_[d * 4];
        ad0 = adv.x; ad1 = adv.y; ad2 = adv.z; ad3 = adv.w;
    } else {
        ad0 = ad_[d];
    }

    float s0 = 0.f, s1 = 0.f, s2 = 0.f, s3 = 0.f;
    float acc0 = 0.f, acc1 = 0.f;
    const int h4 = lane >> 4;      // head for H=4 aggregation (c0 = lane*2, h = c0>>5)
    const int c1 = lane & 31;      // channel for H=1
    const int half_ = lane >> 5;   // edge parity for H=1

    for (int cb = jb; cb < je; cb += 64) {
        const int j = cb + lane;
        const int cnt = min(64, je - cb);
        int sreg = 0;
        float p0 = 0.f, p1 = 0.f, p2 = 0.f, p3 = 0.f;
        if (j < je) {
            sreg = col[j];
            if (H == 4) {
                const float4 a = *(const float4*)&as_[sreg * 4];
                p0 = __expf(leaky_relu(a.x + ad0)); s0 += p0;
                p1 = __expf(leaky_relu(a.y + ad1)); s1 += p1;
                p2 = __expf(leaky_relu(a.z + ad2)); s2 += p2;
                p3 = __expf(leaky_relu(a.w + ad3)); s3 += p3;
            } else {
                p0 = __expf(leaky_relu(as_[sreg] + ad0)); s0 += p0;
            }
        }
        __builtin_amdgcn_wave_barrier();
        sS[w][lane] = sreg;
        if (H == 4) {
            *(float4*)&pS[w][lane * 4] = make_float4(p0, p1, p2, p3);
        } else {
            pS[w][lane] = p0;
        }
        __builtin_amdgcn_wave_barrier();
        if (H == 4) {
            // e2 wave-uniform -> readfirstlane legal (scalar-base h loads)
            #pragma unroll 8
            for (int e2 = 0; e2 < cnt; ++e2) {
                const int s2v = __builtin_amdgcn_readfirstlane(sS[w][e2]);
                const float pp = pS[w][e2 * 4 + h4];
                const float2 v = __half22float2(
                    *(const __half2*)&hbuf[(size_t)s2v * 128 + lane * 2]);
                acc0 = fmaf(pp, v.x, acc0);
                acc1 = fmaf(pp, v.y, acc1);
            }
        } else {
            // e2 DIVERGES across half-waves -> per-lane LDS read (NOT readfirstlane)
            #pragma unroll 8
            for (int e2 = half_; e2 < cnt; e2 += 2) {
                const int s2v = sS[w][e2];
                const float pp = pS[w][e2];
                acc0 = fmaf(pp, __half2float(hbuf[(size_t)s2v * 32 + c1]), acc0);
            }
        }
        __builtin_amdgcn_wave_barrier();   // pS/sS reused next chunk
    }

    // ---- epilogue: reduce denominators, normalize+bias(+relu), write ----
    #pragma unroll
    for (int off = 32; off >= 1; off >>= 1) {
        s0 += __shfl_xor(s0, off);
        if (H == 4) {
            s1 += __shfl_xor(s1, off);
            s2 += __shfl_xor(s2, off);
            s3 += __shfl_xor(s3, off);
        }
    }
    if (H == 4) {
        const float sh = (h4 == 0) ? s0 : (h4 == 1) ? s1 : (h4 == 2) ? s2 : s3;
        const float inv = 1.f / (sh + EPSV);
        const float2 bb = *(const float2*)&bias[lane * 2];
        const float o0 = fmaxf(fmaf(acc0, inv, bb.x), 0.f);
        const float o1 = fmaxf(fmaf(acc1, inv, bb.y), 0.f);
        *(__half2*)&hin[(size_t)d * 128 + lane * 2] = __floats2half2_rn(o0, o1);
    } else {
        acc0 += __shfl_xor(acc0, 32);
        if (lane < 32)
            outf[(size_t)d * 32 + c1] = acc0 / (s0 + EPSV) + bias[c1];
    }
}

extern "C" void kernel_launch(void* const* d_in, const int* in_sizes, int n_in,
                              void* d_out, int out_size, void* d_ws, size_t ws_size,
                              hipStream_t stream)
{
    const float* x     = (const float*)d_in[0];
    const int*   ei    = (const int*)d_in[1];
    const float* W0    = (const float*)d_in[2];
    const float* asrc0 = (const float*)d_in[3];
    const float* adst0 = (const float*)d_in[4];
    const float* b0    = (const float*)d_in[5];
    const float* W1    = (const float*)d_in[6];
    const float* asrc1 = (const float*)d_in[7];
    const float* adst1 = (const float*)d_in[8];
    const float* b1    = (const float*)d_in[9];
    const float* W2    = (const float*)d_in[10];
    const float* asrc2 = (const float*)d_in[11];
    const float* adst2 = (const float*)d_in[12];
    const float* b2    = (const float*)d_in[13];

    const int N = in_sizes[0] / 128;     // 100000
    const int E = in_sizes[1] / 2;       // 1600000
    const int Etot = E + N;              // + self loops
    const int NB = (N + 127) / 128;      // 128-node buckets
    const int* srcs = ei;
    const int* dsts = ei + E;

    __half* hbuf    = (__half*)d_ws;                      // N*128 fp16 (GEMM out)
    __half* hin     = hbuf + (size_t)N * 128;             // N*128 fp16 (gather out)
    float* as_      = (float*)(hin + (size_t)N * 128);    // N*4
    float* ad_      = as_ + (size_t)N * 4;                // N*4
    int* counts     = (int*)(ad_ + (size_t)N * 4);        // N
    int* row_ptr    = counts + N;                         // N+1
    int* bsums      = row_ptr + N + 1;                    // 256
    int* col        = bsums + 256;                        // Etot
    int* bcur       = col + Etot;                         // NB
    unsigned* packed = (unsigned*)(bcur + NB);            // NB*BCAP

    const dim3 blk(256);
    const int gemm128_grid = (N + 31) / 32;
    const int gemm32_grid  = (N + 127) / 128;
    const int nodeH_grid   = (N * 4 + 255) / 256;
    const int node1_grid   = (N + 255) / 256;
    const int edgeE8_grid  = (E + 2047) / 2048;
    const int gather_grid  = (N + 3) / 4;                // 4 waves/block, 1 node/wave
    const int nb1          = (N + 1023) / 1024;

    // ---------------- CSR build via buckets, once ----------------
    hipMemsetAsync(bcur, 0, (size_t)NB * 4, stream);
    bucket_append_kernel<<<edgeE8_grid, blk, 0, stream>>>(srcs, dsts, E, bcur, packed);
    bucket_count_kernel<<<NB, blk, 0, stream>>>(packed, bcur, counts, N);
    scan1_kernel<<<nb1, blk, 0, stream>>>(counts, row_ptr, bsums, N);
    scan2_kernel<<<1, blk, 0, stream>>>(bsums, nb1);
    scan3_kernel<<<(N + 1 + 255) / 256, blk, 0, stream>>>(row_ptr, bsums, N, Etot);
    bucket_scatter_kernel<<<NB, blk, 0, stream>>>(packed, bcur, row_ptr, col, N);

    // ---------------- layer 0 (H=4, C=32) ----------------
    gemm_kernel<128, float><<<gemm128_grid, blk, 0, stream>>>(x, W0, hbuf, N);
    alpha_kernel<4><<<nodeH_grid, blk, 0, stream>>>(hbuf, asrc0, adst0, as_, ad_, N);
    gather_kernel<4><<<gather_grid, blk, 0, stream>>>(row_ptr, col, as_, ad_, hbuf, b0, hin, nullptr, N);

    // ---------------- layer 1 (H=4, C=32) ----------------
    gemm_kernel<128, __half><<<gemm128_grid, blk, 0, stream>>>(hin, W1, hbuf, N);
    alpha_kernel<4><<<nodeH_grid, blk, 0, stream>>>(hbuf, asrc1, adst1, as_, ad_, N);
    gather_kernel<4><<<gather_grid, blk, 0, stream>>>(row_ptr, col, as_, ad_, hbuf, b1, hin, nullptr, N);

    // ---------------- layer 2 (H=1, C=32) ----------------
    gemm_kernel<32, __half><<<gemm32_grid, blk, 0, stream>>>(hin, W2, hbuf, N);
    alpha_kernel<1><<<node1_grid, blk, 0, stream>>>(hbuf, asrc2, adst2, as_, ad_, N);
    gather_kernel<1><<<gather_grid, blk, 0, stream>>>(row_ptr, col, as_, ad_, hbuf, b2, nullptr, (float*)d_out, N);
}

// Round 9
// 606.109 us; speedup vs baseline: 6.3352x; 1.4863x over previous
//
#include <hip/hip_runtime.h>
#include <hip/hip_fp16.h>

#define NEG_SLOPE 0.2f
#define EPSV 1e-16f
#define NXCD 8      // sub-buckets per bucket (XCD split; blockIdx&7 heuristic)
#define BCAP2 448   // per-sub-bucket capacity: mean 256, sigma 16 -> 12 sigma

__device__ __forceinline__ float leaky_relu(float v) {
    return v > 0.f ? v : NEG_SLOPE * v;
}

// ===================== GEMM =====================
// h = X @ W  (X: [nrows,128] XT (fp32 or fp16), W: [128,HC] fp32) -> Hout fp16.
template<int HC, typename XT>
__global__ __launch_bounds__(256)
void gemm_kernel(const XT* __restrict__ X, const float* __restrict__ W,
                 __half* __restrict__ Hout, int nrows)
{
    constexpr int CG = HC / 8;       // col groups (8 cols per thread)
    constexpr int ROWS = 512 / CG;   // rows per block
    __shared__ float Xs[ROWS][132];
    __shared__ float Ws[64 * HC];

    const int t = threadIdx.x;
    const int rowbase = blockIdx.x * ROWS;

    if constexpr (sizeof(XT) == 4) {
        for (int i = t * 4; i < ROWS * 128; i += 256 * 4) {
            const int r = i >> 7;
            const int c = i & 127;
            const int n = rowbase + r;
            float4 v = make_float4(0.f, 0.f, 0.f, 0.f);
            if (n < nrows) v = *(const float4*)&X[(size_t)n * 128 + c];
            *(float4*)&Xs[r][c] = v;
        }
    } else {
        for (int i = t * 8; i < ROWS * 128; i += 256 * 8) {
            const int r = i >> 7;
            const int c = i & 127;
            const int n = rowbase + r;
            union { float4 f4; __half2 h2[4]; } u;
            u.f4 = make_float4(0.f, 0.f, 0.f, 0.f);
            if (n < nrows) u.f4 = *(const float4*)&X[(size_t)n * 128 + c];
            const float2 f0 = __half22float2(u.h2[0]);
            const float2 f1 = __half22float2(u.h2[1]);
            const float2 f2 = __half22float2(u.h2[2]);
            const float2 f3 = __half22float2(u.h2[3]);
            *(float4*)&Xs[r][c]     = make_float4(f0.x, f0.y, f1.x, f1.y);
            *(float4*)&Xs[r][c + 4] = make_float4(f2.x, f2.y, f3.x, f3.y);
        }
    }

    const int cg = t % CG;
    const int rg = t / CG;
    const int r0 = rg * 2;
    const int c0 = cg * 8;

    float acc[2][8];
    #pragma unroll
    for (int i = 0; i < 2; ++i)
        #pragma unroll
        for (int j = 0; j < 8; ++j) acc[i][j] = 0.f;

    for (int kc = 0; kc < 2; ++kc) {
        __syncthreads();
        for (int i = t * 4; i < 64 * HC; i += 256 * 4)
            *(float4*)&Ws[i] = *(const float4*)&W[kc * 64 * HC + i];
        __syncthreads();
        #pragma unroll 8
        for (int kk = 0; kk < 64; ++kk) {
            const float x0 = Xs[r0][kc * 64 + kk];
            const float x1 = Xs[r0 + 1][kc * 64 + kk];
            const float4 w0 = *(const float4*)&Ws[kk * HC + c0];
            const float4 w1 = *(const float4*)&Ws[kk * HC + c0 + 4];
            acc[0][0] = fmaf(x0, w0.x, acc[0][0]);
            acc[0][1] = fmaf(x0, w0.y, acc[0][1]);
            acc[0][2] = fmaf(x0, w0.z, acc[0][2]);
            acc[0][3] = fmaf(x0, w0.w, acc[0][3]);
            acc[0][4] = fmaf(x0, w1.x, acc[0][4]);
            acc[0][5] = fmaf(x0, w1.y, acc[0][5]);
            acc[0][6] = fmaf(x0, w1.z, acc[0][6]);
            acc[0][7] = fmaf(x0, w1.w, acc[0][7]);
            acc[1][0] = fmaf(x1, w0.x, acc[1][0]);
            acc[1][1] = fmaf(x1, w0.y, acc[1][1]);
            acc[1][2] = fmaf(x1, w0.z, acc[1][2]);
            acc[1][3] = fmaf(x1, w0.w, acc[1][3]);
            acc[1][4] = fmaf(x1, w1.x, acc[1][4]);
            acc[1][5] = fmaf(x1, w1.y, acc[1][5]);
            acc[1][6] = fmaf(x1, w1.z, acc[1][6]);
            acc[1][7] = fmaf(x1, w1.w, acc[1][7]);
        }
    }

    #pragma unroll
    for (int i = 0; i < 2; ++i) {
        const int n = rowbase + r0 + i;
        if (n < nrows) {
            union { __half2 h2[4]; float4 f4; } u;
            u.h2[0] = __floats2half2_rn(acc[i][0], acc[i][1]);
            u.h2[1] = __floats2half2_rn(acc[i][2], acc[i][3]);
            u.h2[2] = __floats2half2_rn(acc[i][4], acc[i][5]);
            u.h2[3] = __floats2half2_rn(acc[i][6], acc[i][7]);
            *(float4*)&Hout[(size_t)n * HC + c0] = u.f4;
        }
    }
}

// ===================== per-node attention coefficients (fp16 h) =====================
template<int H>
__global__ __launch_bounds__(256)
void alpha_kernel(const __half* __restrict__ hbuf, const float* __restrict__ a_src,
                  const float* __restrict__ a_dst, float* __restrict__ as_,
                  float* __restrict__ ad_, int n)
{
    const int tid = blockIdx.x * 256 + threadIdx.x;
    if (tid >= n * H) return;
    const int node = tid / H;
    const int h = tid % H;
    const __half2* hp = (const __half2*)(hbuf + (size_t)node * (H * 32) + h * 32);
    const float2* sp = (const float2*)(a_src + h * 32);
    const float2* dp = (const float2*)(a_dst + h * 32);
    float accs = 0.f, accd = 0.f;
    #pragma unroll
    for (int j = 0; j < 16; ++j) {
        const float2 v = __half22float2(hp[j]);
        const float2 sa = sp[j];
        const float2 da = dp[j];
        accs += v.x * sa.x + v.y * sa.y;
        accd += v.x * da.x + v.y * da.y;
    }
    as_[tid] = accs;
    ad_[tid] = accd;
}

// ===================== CSR build via XCD-split 128-node buckets ==================
// Phase 1: append (src | dlocal<<20) into sub-bucket (b, xcd) where
// xcd = blockIdx&7 (round-robin dispatch heuristic -- perf-only assumption).
// Each sub-bucket's counter + tail lines touched by ONE XCD: atomics stay in
// local L2, lines fill before writeback (fixes R8's cross-XCD ping-pong:
// 69MB writes / 4.2G atomic/s for a 6.8MB payload).
__global__ __launch_bounds__(256)
void bucket_append_kernel(const int* __restrict__ srcs, const int* __restrict__ dsts,
                          int E, int* __restrict__ bcur, unsigned* __restrict__ packed)
{
    const int xcd = blockIdx.x & (NXCD - 1);
    const int base = blockIdx.x * 2048 + threadIdx.x;
    #pragma unroll
    for (int k = 0; k < 8; ++k) {
        const int e = base + k * 256;
        if (e < E) {
            const int s = srcs[e];
            const int d = dsts[e];
            const int sb = (d >> 7) * NXCD + xcd;
            const unsigned entry = (unsigned)s | ((unsigned)(d & 127) << 20);
            const int p = atomicAdd(&bcur[sb], 1);
            if (p < BCAP2) packed[(size_t)sb * BCAP2 + p] = entry;
        }
    }
}

// Phase 2: per-bucket LDS histogram over the 8 sub-lists (init 1 = self-loop).
__global__ __launch_bounds__(256)
void bucket_count_kernel(const unsigned* __restrict__ packed, const int* __restrict__ bcur,
                         int* __restrict__ counts, int N)
{
    __shared__ int cnt[128];
    const int t = threadIdx.x;
    const int b = blockIdx.x;
    const int nbase = b * 128;
    if (t < 128) cnt[t] = 1;   // self-loop
    __syncthreads();
    for (int x = 0; x < NXCD; ++x) {
        const int sb = b * NXCD + x;
        const int n = min(bcur[sb], BCAP2);
        const unsigned* bp = packed + (size_t)sb * BCAP2;
        for (int i = t; i < n; i += 256)
            atomicAdd(&cnt[bp[i] >> 20], 1);
    }
    __syncthreads();
    if (t < 128 && nbase + t < N) counts[nbase + t] = cnt[t];
}

__global__ __launch_bounds__(256)
void scan1_kernel(const int* __restrict__ in, int* __restrict__ out,
                  int* __restrict__ bsums, int n)
{
    __shared__ int lds[256];
    const int t = threadIdx.x;
    const int base = blockIdx.x * 1024 + t * 4;
    int v0 = 0, v1 = 0, v2 = 0, v3 = 0;
    if (base + 0 < n) v0 = in[base + 0];
    if (base + 1 < n) v1 = in[base + 1];
    if (base + 2 < n) v2 = in[base + 2];
    if (base + 3 < n) v3 = in[base + 3];
    const int tsum = v0 + v1 + v2 + v3;
    lds[t] = tsum;
    __syncthreads();
    for (int off = 1; off < 256; off <<= 1) {
        const int y = (t >= off) ? lds[t - off] : 0;
        __syncthreads();
        lds[t] += y;
        __syncthreads();
    }
    int excl = lds[t] - tsum;
    if (t == 255) bsums[blockIdx.x] = lds[255];
    if (base + 0 < n) out[base + 0] = excl; excl += v0;
    if (base + 1 < n) out[base + 1] = excl; excl += v1;
    if (base + 2 < n) out[base + 2] = excl; excl += v2;
    if (base + 3 < n) out[base + 3] = excl;
}

__global__ __launch_bounds__(256)
void scan2_kernel(int* __restrict__ bsums, int nb)
{
    __shared__ int lds[256];
    const int t = threadIdx.x;
    const int v = (t < nb) ? bsums[t] : 0;
    lds[t] = v;
    __syncthreads();
    for (int off = 1; off < 256; off <<= 1) {
        const int y = (t >= off) ? lds[t - off] : 0;
        __syncthreads();
        lds[t] += y;
        __syncthreads();
    }
    if (t < nb) bsums[t] = lds[t] - v;   // exclusive
}

__global__ __launch_bounds__(256)
void scan3_kernel(int* __restrict__ row_ptr, const int* __restrict__ bsums,
                  int n, int etot)
{
    const int idx = blockIdx.x * 256 + threadIdx.x;
    if (idx < n) row_ptr[idx] += bsums[idx >> 10];
    if (idx == n) row_ptr[n] = etot;
}

// Phase 3: per-bucket scatter of the 8 sub-lists into exact CSR (contiguous span).
__global__ __launch_bounds__(256)
void bucket_scatter_kernel(const unsigned* __restrict__ packed, const int* __restrict__ bcur,
                           const int* __restrict__ row_ptr, int* __restrict__ col, int N)
{
    __shared__ int cur[128];
    const int t = threadIdx.x;
    const int b = blockIdx.x;
    const int nbase = b * 128;
    if (t < 128 && nbase + t < N) cur[t] = row_ptr[nbase + t];
    __syncthreads();
    if (t < 128 && nbase + t < N) {            // self-loop
        const int p = atomicAdd(&cur[t], 1);
        col[p] = nbase + t;
    }
    for (int x = 0; x < NXCD; ++x) {
        const int sb = b * NXCD + x;
        const int n = min(bcur[sb], BCAP2);
        const unsigned* bp = packed + (size_t)sb * BCAP2;
        for (int i = t; i < n; i += 256) {
            const unsigned en = bp[i];
            const int p = atomicAdd(&cur[en >> 20], 1);
            col[p] = en & 0xFFFFF;
        }
    }
}

// ===================== fused edge softmax + aggregation + next-layer input prep =====
// one wave per destination node; alpha = exp(e)/sum(exp(e)) (shift-free; data bounds
// |e|<~5 so no overflow). Epilogue fuses normalize + bias + (ReLU+fp16 for H=4 |
// final fp32 out for H=1).
// NOTE: readfirstlane on sS[...] legal ONLY for wave-uniform index (H==4 path).
template<int H>
__global__ __launch_bounds__(256)
void gather_kernel(const int* __restrict__ row_ptr, const int* __restrict__ col,
                   const float* __restrict__ as_, const float* __restrict__ ad_,
                   const __half* __restrict__ hbuf, const float* __restrict__ bias,
                   __half* __restrict__ hin, float* __restrict__ outf, int N)
{
    __shared__ float pS[4][64 * H];
    __shared__ int   sS[4][64];
    const int w = threadIdx.x >> 6;
    const int lane = threadIdx.x & 63;
    const int d = blockIdx.x * 4 + w;
    if (d >= N) return;
    const int jb = __builtin_amdgcn_readfirstlane(row_ptr[d]);
    const int je = __builtin_amdgcn_readfirstlane(row_ptr[d + 1]);

    float ad0 = 0.f, ad1 = 0.f, ad2 = 0.f, ad3 = 0.f;
    if (H == 4) {
        const float4 adv = *(const float4*)&ad_[d * 4];
        ad0 = adv.x; ad1 = adv.y; ad2 = adv.z; ad3 = adv.w;
    } else {
        ad0 = ad_[d];
    }

    float s0 = 0.f, s1 = 0.f, s2 = 0.f, s3 = 0.f;
    float acc0 = 0.f, acc1 = 0.f;
    const int h4 = lane >> 4;      // head for H=4 aggregation (c0 = lane*2, h = c0>>5)
    const int c1 = lane & 31;      // channel for H=1
    const int half_ = lane >> 5;   // edge parity for H=1

    for (int cb = jb; cb < je; cb += 64) {
        const int j = cb + lane;
        const int cnt = min(64, je - cb);
        int sreg = 0;
        float p0 = 0.f, p1 = 0.f, p2 = 0.f, p3 = 0.f;
        if (j < je) {
            sreg = col[j];
            if (H == 4) {
                const float4 a = *(const float4*)&as_[sreg * 4];
                p0 = __expf(leaky_relu(a.x + ad0)); s0 += p0;
                p1 = __expf(leaky_relu(a.y + ad1)); s1 += p1;
                p2 = __expf(leaky_relu(a.z + ad2)); s2 += p2;
                p3 = __expf(leaky_relu(a.w + ad3)); s3 += p3;
            } else {
                p0 = __expf(leaky_relu(as_[sreg] + ad0)); s0 += p0;
            }
        }
        __builtin_amdgcn_wave_barrier();
        sS[w][lane] = sreg;
        if (H == 4) {
            *(float4*)&pS[w][lane * 4] = make_float4(p0, p1, p2, p3);
        } else {
            pS[w][lane] = p0;
        }
        __builtin_amdgcn_wave_barrier();
        if (H == 4) {
            // e2 wave-uniform -> readfirstlane legal (scalar-base h loads)
            #pragma unroll 8
            for (int e2 = 0; e2 < cnt; ++e2) {
                const int s2v = __builtin_amdgcn_readfirstlane(sS[w][e2]);
                const float pp = pS[w][e2 * 4 + h4];
                const float2 v = __half22float2(
                    *(const __half2*)&hbuf[(size_t)s2v * 128 + lane * 2]);
                acc0 = fmaf(pp, v.x, acc0);
                acc1 = fmaf(pp, v.y, acc1);
            }
        } else {
            // e2 DIVERGES across half-waves -> per-lane LDS read (NOT readfirstlane)
            #pragma unroll 8
            for (int e2 = half_; e2 < cnt; e2 += 2) {
                const int s2v = sS[w][e2];
                const float pp = pS[w][e2];
                acc0 = fmaf(pp, __half2float(hbuf[(size_t)s2v * 32 + c1]), acc0);
            }
        }
        __builtin_amdgcn_wave_barrier();   // pS/sS reused next chunk
    }

    // ---- epilogue: reduce denominators, normalize+bias(+relu), write ----
    #pragma unroll
    for (int off = 32; off >= 1; off >>= 1) {
        s0 += __shfl_xor(s0, off);
        if (H == 4) {
            s1 += __shfl_xor(s1, off);
            s2 += __shfl_xor(s2, off);
            s3 += __shfl_xor(s3, off);
        }
    }
    if (H == 4) {
        const float sh = (h4 == 0) ? s0 : (h4 == 1) ? s1 : (h4 == 2) ? s2 : s3;
        const float inv = 1.f / (sh + EPSV);
        const float2 bb = *(const float2*)&bias[lane * 2];
        const float o0 = fmaxf(fmaf(acc0, inv, bb.x), 0.f);
        const float o1 = fmaxf(fmaf(acc1, inv, bb.y), 0.f);
        *(__half2*)&hin[(size_t)d * 128 + lane * 2] = __floats2half2_rn(o0, o1);
    } else {
        acc0 += __shfl_xor(acc0, 32);
        if (lane < 32)
            outf[(size_t)d * 32 + c1] = acc0 / (s0 + EPSV) + bias[c1];
    }
}

extern "C" void kernel_launch(void* const* d_in, const int* in_sizes, int n_in,
                              void* d_out, int out_size, void* d_ws, size_t ws_size,
                              hipStream_t stream)
{
    const float* x     = (const float*)d_in[0];
    const int*   ei    = (const int*)d_in[1];
    const float* W0    = (const float*)d_in[2];
    const float* asrc0 = (const float*)d_in[3];
    const float* adst0 = (const float*)d_in[4];
    const float* b0    = (const float*)d_in[5];
    const float* W1    = (const float*)d_in[6];
    const float* asrc1 = (const float*)d_in[7];
    const float* adst1 = (const float*)d_in[8];
    const float* b1    = (const float*)d_in[9];
    const float* W2    = (const float*)d_in[10];
    const float* asrc2 = (const float*)d_in[11];
    const float* adst2 = (const float*)d_in[12];
    const float* b2    = (const float*)d_in[13];

    const int N = in_sizes[0] / 128;     // 100000
    const int E = in_sizes[1] / 2;       // 1600000
    const int Etot = E + N;              // + self loops
    const int NB = (N + 127) / 128;      // 128-node buckets
    const int* srcs = ei;
    const int* dsts = ei + E;

    __half* hbuf    = (__half*)d_ws;                      // N*128 fp16 (GEMM out)
    __half* hin     = hbuf + (size_t)N * 128;             // N*128 fp16 (gather out)
    float* as_      = (float*)(hin + (size_t)N * 128);    // N*4
    float* ad_      = as_ + (size_t)N * 4;                // N*4
    int* counts     = (int*)(ad_ + (size_t)N * 4);        // N
    int* row_ptr    = counts + N;                         // N+1
    int* bsums      = row_ptr + N + 1;                    // 256
    int* col        = bsums + 256;                        // Etot
    int* bcur       = col + Etot;                         // NB*NXCD
    unsigned* packed = (unsigned*)(bcur + NB * NXCD);     // NB*NXCD*BCAP2

    const dim3 blk(256);
    const int gemm128_grid = (N + 31) / 32;
    const int gemm32_grid  = (N + 127) / 128;
    const int nodeH_grid   = (N * 4 + 255) / 256;
    const int node1_grid   = (N + 255) / 256;
    const int edgeE8_grid  = (E + 2047) / 2048;
    const int gather_grid  = (N + 3) / 4;                // 4 waves/block, 1 node/wave
    const int nb1          = (N + 1023) / 1024;

    // ---------------- CSR build via XCD-split buckets, once ----------------
    hipMemsetAsync(bcur, 0, (size_t)NB * NXCD * 4, stream);
    bucket_append_kernel<<<edgeE8_grid, blk, 0, stream>>>(srcs, dsts, E, bcur, packed);
    bucket_count_kernel<<<NB, blk, 0, stream>>>(packed, bcur, counts, N);
    scan1_kernel<<<nb1, blk, 0, stream>>>(counts, row_ptr, bsums, N);
    scan2_kernel<<<1, blk, 0, stream>>>(bsums, nb1);
    scan3_kernel<<<(N + 1 + 255) / 256, blk, 0, stream>>>(row_ptr, bsums, N, Etot);
    bucket_scatter_kernel<<<NB, blk, 0, stream>>>(packed, bcur, row_ptr, col, N);

    // ---------------- layer 0 (H=4, C=32) ----------------
    gemm_kernel<128, float><<<gemm128_grid, blk, 0, stream>>>(x, W0, hbuf, N);
    alpha_kernel<4><<<nodeH_grid, blk, 0, stream>>>(hbuf, asrc0, adst0, as_, ad_, N);
    gather_kernel<4><<<gather_grid, blk, 0, stream>>>(row_ptr, col, as_, ad_, hbuf, b0, hin, nullptr, N);

    // ---------------- layer 1 (H=4, C=32) ----------------
    gemm_kernel<128, __half><<<gemm128_grid, blk, 0, stream>>>(hin, W1, hbuf, N);
    alpha_kernel<4><<<nodeH_grid, blk, 0, stream>>>(hbuf, asrc1, adst1, as_, ad_, N);
    gather_kernel<4><<<gather_grid, blk, 0, stream>>>(row_ptr, col, as_, ad_, hbuf, b1, hin, nullptr, N);

    // ---------------- layer 2 (H=1, C=32) ----------------
    gemm_kernel<32, __half><<<gemm32_grid, blk, 0, stream>>>(hin, W2, hbuf, N);
    alpha_kernel<1><<<node1_grid, blk, 0, stream>>>(hbuf, asrc2, adst2, as_, ad_, N);
    gather_kernel<1><<<gather_grid, blk, 0, stream>>>(row_ptr, col, as_, ad_, hbuf, b2, nullptr, (float*)d_out, N);
}

// Round 10
// 531.863 us; speedup vs baseline: 7.2196x; 1.1396x over previous
//
#include <hip/hip_runtime.h>
#include <hip/hip_fp16.h>

#define NEG_SLOPE 0.2f
#define EPSV 1e-16f
#define NXCD 8      // sub-buckets per bucket (XCD split; blockIdx&7 heuristic)
#define BCAP2 448   // per-sub-bucket capacity: mean 256, sigma 16 -> 12 sigma

typedef _Float16 half8 __attribute__((ext_vector_type(8)));
typedef float floatx4 __attribute__((ext_vector_type(4)));

__device__ __forceinline__ float leaky_relu(float v) {
    return v > 0.f ? v : NEG_SLOPE * v;
}

// ===================== weight prep: W[128][HC] fp32 -> Wt[HC][128] fp16 ==========
__global__ __launch_bounds__(256)
void wconv_kernel(const float* __restrict__ W, __half* __restrict__ Wt, int HC)
{
    const int idx = blockIdx.x * 256 + threadIdx.x;
    if (idx < 128 * HC) {
        const int k = idx / HC;
        const int c = idx - k * HC;
        Wt[c * 128 + k] = __float2half(W[idx]);
    }
}

// ===================== MFMA GEMM =====================
// h = X @ W (X: [nrows,128] fp32|fp16, Wt: [HC][128] fp16) -> Hout fp16.
// One wave per 16 rows. A-frag: lane holds X[row0+(l&15)][kk*32+(l>>4)*8 ..+7]
// (lanes r,r+16,r+32,r+48 cover 64 contiguous bytes -> coalesced). B-frag:
// Wt[ct*16+(l&15)][kk*32+(l>>4)*8 ..+7]. C/D: col=lane&15, row=(lane>>4)*4+j
// (m89-verified layout). No LDS, no barriers.
template<int HC, typename XT>
__global__ __launch_bounds__(256)
void mfma_gemm_kernel(const XT* __restrict__ X, const __half* __restrict__ Wt,
                      __half* __restrict__ Hout, int nrows)
{
    const int wid = (blockIdx.x * 256 + threadIdx.x) >> 6;
    const int lane = threadIdx.x & 63;
    const int row0 = wid * 16;
    if (row0 >= nrows) return;
    const int r = lane & 15;
    const int kq = lane >> 4;
    const int arow = min(row0 + r, nrows - 1);

    half8 a[4];
    #pragma unroll
    for (int kk = 0; kk < 4; ++kk) {
        const int k0 = kk * 32 + kq * 8;
        if constexpr (sizeof(XT) == 4) {
            const float4 f0 = *(const float4*)&X[(size_t)arow * 128 + k0];
            const float4 f1 = *(const float4*)&X[(size_t)arow * 128 + k0 + 4];
            half8 v;
            v[0] = (_Float16)f0.x; v[1] = (_Float16)f0.y;
            v[2] = (_Float16)f0.z; v[3] = (_Float16)f0.w;
            v[4] = (_Float16)f1.x; v[5] = (_Float16)f1.y;
            v[6] = (_Float16)f1.z; v[7] = (_Float16)f1.w;
            a[kk] = v;
        } else {
            a[kk] = *(const half8*)&X[(size_t)arow * 128 + k0];
        }
    }

    #pragma unroll
    for (int ct = 0; ct < HC / 16; ++ct) {
        floatx4 acc = {0.f, 0.f, 0.f, 0.f};
        #pragma unroll
        for (int kk = 0; kk < 4; ++kk) {
            const half8 b = *(const half8*)&Wt[(size_t)(ct * 16 + r) * 128 + kk * 32 + kq * 8];
            acc = __builtin_amdgcn_mfma_f32_16x16x32_f16(a[kk], b, acc, 0, 0, 0);
        }
        #pragma unroll
        for (int j = 0; j < 4; ++j) {
            const int orow = row0 + kq * 4 + j;
            if (orow < nrows)
                Hout[(size_t)orow * HC + ct * 16 + r] = __float2half(acc[j]);
        }
    }
}

// ===================== per-node attention coefficients (fp16 h) =====================
template<int H>
__global__ __launch_bounds__(256)
void alpha_kernel(const __half* __restrict__ hbuf, const float* __restrict__ a_src,
                  const float* __restrict__ a_dst, float* __restrict__ as_,
                  float* __restrict__ ad_, int n)
{
    const int tid = blockIdx.x * 256 + threadIdx.x;
    if (tid >= n * H) return;
    const int node = tid / H;
    const int h = tid % H;
    const __half2* hp = (const __half2*)(hbuf + (size_t)node * (H * 32) + h * 32);
    const float2* sp = (const float2*)(a_src + h * 32);
    const float2* dp = (const float2*)(a_dst + h * 32);
    float accs = 0.f, accd = 0.f;
    #pragma unroll
    for (int j = 0; j < 16; ++j) {
        const float2 v = __half22float2(hp[j]);
        const float2 sa = sp[j];
        const float2 da = dp[j];
        accs += v.x * sa.x + v.y * sa.y;
        accd += v.x * da.x + v.y * da.y;
    }
    as_[tid] = accs;
    ad_[tid] = accd;
}

// ===================== CSR build via XCD-split 128-node buckets ==================
__global__ __launch_bounds__(256)
void bucket_append_kernel(const int* __restrict__ srcs, const int* __restrict__ dsts,
                          int E, int* __restrict__ bcur, unsigned* __restrict__ packed)
{
    const int xcd = blockIdx.x & (NXCD - 1);
    const int base = blockIdx.x * 2048 + threadIdx.x;
    #pragma unroll
    for (int k = 0; k < 8; ++k) {
        const int e = base + k * 256;
        if (e < E) {
            const int s = srcs[e];
            const int d = dsts[e];
            const int sb = (d >> 7) * NXCD + xcd;
            const unsigned entry = (unsigned)s | ((unsigned)(d & 127) << 20);
            const int p = atomicAdd(&bcur[sb], 1);
            if (p < BCAP2) packed[(size_t)sb * BCAP2 + p] = entry;
        }
    }
}

__global__ __launch_bounds__(256)
void bucket_count_kernel(const unsigned* __restrict__ packed, const int* __restrict__ bcur,
                         int* __restrict__ counts, int N)
{
    __shared__ int cnt[128];
    const int t = threadIdx.x;
    const int b = blockIdx.x;
    const int nbase = b * 128;
    if (t < 128) cnt[t] = 1;   // self-loop
    __syncthreads();
    for (int x = 0; x < NXCD; ++x) {
        const int sb = b * NXCD + x;
        const int n = min(bcur[sb], BCAP2);
        const unsigned* bp = packed + (size_t)sb * BCAP2;
        for (int i = t; i < n; i += 256)
            atomicAdd(&cnt[bp[i] >> 20], 1);
    }
    __syncthreads();
    if (t < 128 && nbase + t < N) counts[nbase + t] = cnt[t];
}

__global__ __launch_bounds__(256)
void scan1_kernel(const int* __restrict__ in, int* __restrict__ out,
                  int* __restrict__ bsums, int n)
{
    __shared__ int lds[256];
    const int t = threadIdx.x;
    const int base = blockIdx.x * 1024 + t * 4;
    int v0 = 0, v1 = 0, v2 = 0, v3 = 0;
    if (base + 0 < n) v0 = in[base + 0];
    if (base + 1 < n) v1 = in[base + 1];
    if (base + 2 < n) v2 = in[base + 2];
    if (base + 3 < n) v3 = in[base + 3];
    const int tsum = v0 + v1 + v2 + v3;
    lds[t] = tsum;
    __syncthreads();
    for (int off = 1; off < 256; off <<= 1) {
        const int y = (t >= off) ? lds[t - off] : 0;
        __syncthreads();
        lds[t] += y;
        __syncthreads();
    }
    int excl = lds[t] - tsum;
    if (t == 255) bsums[blockIdx.x] = lds[255];
    if (base + 0 < n) out[base + 0] = excl; excl += v0;
    if (base + 1 < n) out[base + 1] = excl; excl += v1;
    if (base + 2 < n) out[base + 2] = excl; excl += v2;
    if (base + 3 < n) out[base + 3] = excl;
}

__global__ __launch_bounds__(256)
void scan2_kernel(int* __restrict__ bsums, int nb)
{
    __shared__ int lds[256];
    const int t = threadIdx.x;
    const int v = (t < nb) ? bsums[t] : 0;
    lds[t] = v;
    __syncthreads();
    for (int off = 1; off < 256; off <<= 1) {
        const int y = (t >= off) ? lds[t - off] : 0;
        __syncthreads();
        lds[t] += y;
        __syncthreads();
    }
    if (t < nb) bsums[t] = lds[t] - v;   // exclusive
}

__global__ __launch_bounds__(256)
void scan3_kernel(int* __restrict__ row_ptr, const int* __restrict__ bsums,
                  int n, int etot)
{
    const int idx = blockIdx.x * 256 + threadIdx.x;
    if (idx < n) row_ptr[idx] += bsums[idx >> 10];
    if (idx == n) row_ptr[n] = etot;
}

__global__ __launch_bounds__(256)
void bucket_scatter_kernel(const unsigned* __restrict__ packed, const int* __restrict__ bcur,
                           const int* __restrict__ row_ptr, int* __restrict__ col, int N)
{
    __shared__ int cur[128];
    const int t = threadIdx.x;
    const int b = blockIdx.x;
    const int nbase = b * 128;
    if (t < 128 && nbase + t < N) cur[t] = row_ptr[nbase + t];
    __syncthreads();
    if (t < 128 && nbase + t < N) {            // self-loop
        const int p = atomicAdd(&cur[t], 1);
        col[p] = nbase + t;
    }
    for (int x = 0; x < NXCD; ++x) {
        const int sb = b * NXCD + x;
        const int n = min(bcur[sb], BCAP2);
        const unsigned* bp = packed + (size_t)sb * BCAP2;
        for (int i = t; i < n; i += 256) {
            const unsigned en = bp[i];
            const int p = atomicAdd(&cur[en >> 20], 1);
            col[p] = en & 0xFFFFF;
        }
    }
}

// ===================== fused edge softmax + aggregation + next-layer input prep =====
// one wave per destination node; alpha = exp(e)/sum(exp(e)) (shift-free; data bounds
// |e|<~5). Epilogue fuses normalize + bias + (ReLU+fp16 for H=4 | fp32 out for H=1).
// H=4: 1 edge/iter (full 256B row, uniform e2 -> readfirstlane scalar-base loads).
// H=1: 4 edges/iter (quarter-waves; 16 lanes x half2 = 64B row; e2 divergent ->
//      plain per-lane LDS reads, 4 distinct addrs/wave = ~free per m136).
template<int H>
__global__ __launch_bounds__(256)
void gather_kernel(const int* __restrict__ row_ptr, const int* __restrict__ col,
                   const float* __restrict__ as_, const float* __restrict__ ad_,
                   const __half* __restrict__ hbuf, const float* __restrict__ bias,
                   __half* __restrict__ hin, float* __restrict__ outf, int N)
{
    __shared__ float pS[4][64 * H];
    __shared__ int   sS[4][64];
    const int w = threadIdx.x >> 6;
    const int lane = threadIdx.x & 63;
    const int d = blockIdx.x * 4 + w;
    if (d >= N) return;
    const int jb = __builtin_amdgcn_readfirstlane(row_ptr[d]);
    const int je = __builtin_amdgcn_readfirstlane(row_ptr[d + 1]);

    float ad0 = 0.f, ad1 = 0.f, ad2 = 0.f, ad3 = 0.f;
    if (H == 4) {
        const float4 adv = *(const float4*)&ad_[d * 4];
        ad0 = adv.x; ad1 = adv.y; ad2 = adv.z; ad3 = adv.w;
    } else {
        ad0 = ad_[d];
    }

    float s0 = 0.f, s1 = 0.f, s2 = 0.f, s3 = 0.f;
    float acc0 = 0.f, acc1 = 0.f;
    const int h4 = lane >> 4;      // head for H=4 aggregation (c0 = lane*2, h = c0>>5)
    const int q = lane >> 4;       // quarter-wave id (H=1 edge parity)
    const int cq = lane & 15;      // channel-pair id for H=1

    for (int cb = jb; cb < je; cb += 64) {
        const int j = cb + lane;
        const int cnt = min(64, je - cb);
        int sreg = 0;
        float p0 = 0.f, p1 = 0.f, p2 = 0.f, p3 = 0.f;
        if (j < je) {
            sreg = col[j];
            if (H == 4) {
                const float4 a = *(const float4*)&as_[sreg * 4];
                p0 = __expf(leaky_relu(a.x + ad0)); s0 += p0;
                p1 = __expf(leaky_relu(a.y + ad1)); s1 += p1;
                p2 = __expf(leaky_relu(a.z + ad2)); s2 += p2;
                p3 = __expf(leaky_relu(a.w + ad3)); s3 += p3;
            } else {
                p0 = __expf(leaky_relu(as_[sreg] + ad0)); s0 += p0;
            }
        }
        __builtin_amdgcn_wave_barrier();
        sS[w][lane] = sreg;
        if (H == 4) {
            *(float4*)&pS[w][lane * 4] = make_float4(p0, p1, p2, p3);
        } else {
            pS[w][lane] = p0;
        }
        __builtin_amdgcn_wave_barrier();
        if (H == 4) {
            // e2 wave-uniform -> readfirstlane legal (scalar-base h loads)
            #pragma unroll 8
            for (int e2 = 0; e2 < cnt; ++e2) {
                const int s2v = __builtin_amdgcn_readfirstlane(sS[w][e2]);
                const float pp = pS[w][e2 * 4 + h4];
                const float2 v = __half22float2(
                    *(const __half2*)&hbuf[(size_t)s2v * 128 + lane * 2]);
                acc0 = fmaf(pp, v.x, acc0);
                acc1 = fmaf(pp, v.y, acc1);
            }
        } else {
            // e2 DIVERGES across quarter-waves -> per-lane LDS reads
            #pragma unroll 8
            for (int e2 = q; e2 < cnt; e2 += 4) {
                const int s2v = sS[w][e2];
                const float pp = pS[w][e2];
                const float2 v = __half22float2(
                    *(const __half2*)&hbuf[(size_t)s2v * 32 + cq * 2]);
                acc0 = fmaf(pp, v.x, acc0);
                acc1 = fmaf(pp, v.y, acc1);
            }
        }
        __builtin_amdgcn_wave_barrier();   // pS/sS reused next chunk
    }

    // ---- epilogue: reduce denominators, normalize+bias(+relu), write ----
    #pragma unroll
    for (int off = 32; off >= 1; off >>= 1) {
        s0 += __shfl_xor(s0, off);
        if (H == 4) {
            s1 += __shfl_xor(s1, off);
            s2 += __shfl_xor(s2, off);
            s3 += __shfl_xor(s3, off);
        }
    }
    if (H == 4) {
        const float sh = (h4 == 0) ? s0 : (h4 == 1) ? s1 : (h4 == 2) ? s2 : s3;
        const float inv = 1.f / (sh + EPSV);
        const float2 bb = *(const float2*)&bias[lane * 2];
        const float o0 = fmaxf(fmaf(acc0, inv, bb.x), 0.f);
        const float o1 = fmaxf(fmaf(acc1, inv, bb.y), 0.f);
        *(__half2*)&hin[(size_t)d * 128 + lane * 2] = __floats2half2_rn(o0, o1);
    } else {
        acc0 += __shfl_xor(acc0, 16); acc0 += __shfl_xor(acc0, 32);
        acc1 += __shfl_xor(acc1, 16); acc1 += __shfl_xor(acc1, 32);
        if (lane < 16) {
            const float inv = 1.f / (s0 + EPSV);
            const float2 bb = *(const float2*)&bias[cq * 2];
            *(float2*)&outf[(size_t)d * 32 + cq * 2] =
                make_float2(fmaf(acc0, inv, bb.x), fmaf(acc1, inv, bb.y));
        }
    }
}

extern "C" void kernel_launch(void* const* d_in, const int* in_sizes, int n_in,
                              void* d_out, int out_size, void* d_ws, size_t ws_size,
                              hipStream_t stream)
{
    const float* x     = (const float*)d_in[0];
    const int*   ei    = (const int*)d_in[1];
    const float* W0    = (const float*)d_in[2];
    const float* asrc0 = (const float*)d_in[3];
    const float* adst0 = (const float*)d_in[4];
    const float* b0    = (const float*)d_in[5];
    const float* W1    = (const float*)d_in[6];
    const float* asrc1 = (const float*)d_in[7];
    const float* adst1 = (const float*)d_in[8];
    const float* b1    = (const float*)d_in[9];
    const float* W2    = (const float*)d_in[10];
    const float* asrc2 = (const float*)d_in[11];
    const float* adst2 = (const float*)d_in[12];
    const float* b2    = (const float*)d_in[13];

    const int N = in_sizes[0] / 128;     // 100000
    const int E = in_sizes[1] / 2;       // 1600000
    const int Etot = E + N;              // + self loops
    const int NB = (N + 127) / 128;      // 128-node buckets
    const int* srcs = ei;
    const int* dsts = ei + E;

    __half* hbuf    = (__half*)d_ws;                      // N*128 fp16 (GEMM out)
    __half* hin     = hbuf + (size_t)N * 128;             // N*128 fp16 (gather out)
    float* as_      = (float*)(hin + (size_t)N * 128);    // N*4
    float* ad_      = as_ + (size_t)N * 4;                // N*4
    __half* Wt0     = (__half*)(ad_ + (size_t)N * 4);     // 128*128
    __half* Wt1     = Wt0 + 128 * 128;                    // 128*128
    __half* Wt2     = Wt1 + 128 * 128;                    // 32*128
    int* counts     = (int*)(Wt2 + 32 * 128);             // N
    int* row_ptr    = counts + N;                         // N+1
    int* bsums      = row_ptr + N + 1;                    // 256
    int* col        = bsums + 256;                        // Etot
    int* bcur       = col + Etot;                         // NB*NXCD
    unsigned* packed = (unsigned*)(bcur + NB * NXCD);     // NB*NXCD*BCAP2

    const dim3 blk(256);
    const int gemm_grid    = ((N + 15) / 16 + 3) / 4;    // 1 wave / 16 rows
    const int nodeH_grid   = (N * 4 + 255) / 256;
    const int node1_grid   = (N + 255) / 256;
    const int edgeE8_grid  = (E + 2047) / 2048;
    const int gather_grid  = (N + 3) / 4;                // 4 waves/block, 1 node/wave
    const int nb1          = (N + 1023) / 1024;

    // ---------------- weight prep + CSR build, once ----------------
    wconv_kernel<<<(128 * 128 + 255) / 256, blk, 0, stream>>>(W0, Wt0, 128);
    wconv_kernel<<<(128 * 128 + 255) / 256, blk, 0, stream>>>(W1, Wt1, 128);
    wconv_kernel<<<(128 * 32 + 255) / 256, blk, 0, stream>>>(W2, Wt2, 32);
    hipMemsetAsync(bcur, 0, (size_t)NB * NXCD * 4, stream);
    bucket_append_kernel<<<edgeE8_grid, blk, 0, stream>>>(srcs, dsts, E, bcur, packed);
    bucket_count_kernel<<<NB, blk, 0, stream>>>(packed, bcur, counts, N);
    scan1_kernel<<<nb1, blk, 0, stream>>>(counts, row_ptr, bsums, N);
    scan2_kernel<<<1, blk, 0, stream>>>(bsums, nb1);
    scan3_kernel<<<(N + 1 + 255) / 256, blk, 0, stream>>>(row_ptr, bsums, N, Etot);
    bucket_scatter_kernel<<<NB, blk, 0, stream>>>(packed, bcur, row_ptr, col, N);

    // ---------------- layer 0 (H=4, C=32) ----------------
    mfma_gemm_kernel<128, float><<<gemm_grid, blk, 0, stream>>>(x, Wt0, hbuf, N);
    alpha_kernel<4><<<nodeH_grid, blk, 0, stream>>>(hbuf, asrc0, adst0, as_, ad_, N);
    gather_kernel<4><<<gather_grid, blk, 0, stream>>>(row_ptr, col, as_, ad_, hbuf, b0, hin, nullptr, N);

    // ---------------- layer 1 (H=4, C=32) ----------------
    mfma_gemm_kernel<128, __half><<<gemm_grid, blk, 0, stream>>>(hin, Wt1, hbuf, N);
    alpha_kernel<4><<<nodeH_grid, blk, 0, stream>>>(hbuf, asrc1, adst1, as_, ad_, N);
    gather_kernel<4><<<gather_grid, blk, 0, stream>>>(row_ptr, col, as_, ad_, hbuf, b1, hin, nullptr, N);

    // ---------------- layer 2 (H=1, C=32) ----------------
    mfma_gemm_kernel<32, __half><<<gemm_grid, blk, 0, stream>>>(hin, Wt2, hbuf, N);
    alpha_kernel<1><<<node1_grid, blk, 0, stream>>>(hbuf, asrc2, adst2, as_, ad_, N);
    gather_kernel<1><<<gather_grid, blk, 0, stream>>>(row_ptr, col, as_, ad_, hbuf, b2, nullptr, (float*)d_out, N);
}